// Round 5
// baseline (102.404 us; speedup 1.0000x reference)
//
#include <hip/hip_runtime.h>

#define RATE 0.001f

typedef float f2 __attribute__((ext_vector_type(2)));
typedef float f4 __attribute__((ext_vector_type(4)));

static __device__ __forceinline__ f2 splat2(float v) { f2 r; r.x = v; r.y = v; return r; }
static __device__ __forceinline__ f2 vfma2(f2 a, f2 b, f2 c) { return __builtin_elementwise_fma(a, b, c); }

// Fused Hebbian layer, one kernel per layer, no LDS.
// Block = 512 threads = 8 waves; wave w owns batch row b=w; block owns output neuron o.
// out[b,o] = vj + scale*( sum_i a_i*(sum_h relu(a_i*p_h + w_oi*q_h + vj*r_h + c1b_h)*c2w_h)
//                          + c2b * sum_i a_i ),  vj = relu(dot(a_b, w_o) + bias_o)
// All reductions wave-local (wave sees only its own b). h (8) packed into 4 x f2
// -> v_pk_fma_f32 / v_pk_max_f32.
// __launch_bounds__(512, 8): pin <=64 VGPR so each SIMD holds 8 waves (occupancy
// cliff at 65 VGPRs would halve waves/SIMD and expose the shuffle/load latency).
template<int I>
__global__ __launch_bounds__(512, 8) void hebb_layer(
    const float* __restrict__ vi,    // (8, I)
    const float* __restrict__ w,     // (O, I)
    const float* __restrict__ bias,  // (O,)
    const float* __restrict__ c1w,   // (8, 3): p,q,r
    const float* __restrict__ c1b,   // (8,)
    const float* __restrict__ c2w,   // (8,)
    const float* __restrict__ c2b_p, // scalar
    const int*   __restrict__ bn_p,  // scalar batch_num
    float* __restrict__ out,         // (8, O)
    int O)
{
    const int o    = blockIdx.x;
    const int tid  = threadIdx.x;
    const int lane = tid & 63;
    const int b    = tid >> 6;       // wave id == batch row

    const float* __restrict__ wrow = w  + (size_t)o * I;
    const float* __restrict__ arow = vi + (size_t)b * I;

    constexpr int ITERS = I / 256;   // 64 lanes * 4 floats per iter

    // ---- pass 1: dot(a_b, w_o) and rowsum(a_b), packed, wave-local ----
    f2 dot2 = splat2(0.f), ss2 = splat2(0.f);
    for (int it = 0; it < ITERS; ++it) {
        const int base = it * 256 + lane * 4;
        const f4 wv = *(const f4*)(wrow + base);
        const f4 av = *(const f4*)(arow + base);
        f2 alo; alo.x = av.x; alo.y = av.y;
        f2 ahi; ahi.x = av.z; ahi.y = av.w;
        f2 wlo; wlo.x = wv.x; wlo.y = wv.y;
        f2 whi; whi.x = wv.z; whi.y = wv.w;
        dot2 = vfma2(alo, wlo, dot2);
        dot2 = vfma2(ahi, whi, dot2);
        ss2  = ss2 + alo;
        ss2  = ss2 + ahi;
    }
    float dot = dot2.x + dot2.y;
    float ss  = ss2.x + ss2.y;
#pragma unroll
    for (int off = 1; off < 64; off <<= 1) {
        dot += __shfl_xor(dot, off, 64);
        ss  += __shfl_xor(ss,  off, 64);
    }
    const float vj = fmaxf(dot + bias[o], 0.f);

    // steady-state constants: p,q,c2 packed pairs; K[h] = vj*r_h + c1b_h
    f2 p2[4], q2[4], c22[4], K2[4];
#pragma unroll
    for (int j = 0; j < 4; ++j) {
        p2[j].x  = c1w[(2*j)*3 + 0];  p2[j].y  = c1w[(2*j+1)*3 + 0];
        q2[j].x  = c1w[(2*j)*3 + 1];  q2[j].y  = c1w[(2*j+1)*3 + 1];
        c22[j].x = c2w[2*j];          c22[j].y = c2w[2*j+1];
        K2[j].x  = fmaf(vj, c1w[(2*j)*3 + 2], c1b[2*j]);
        K2[j].y  = fmaf(vj, c1w[(2*j+1)*3 + 2], c1b[2*j+1]);
    }
    const float c2b   = *c2b_p;
    const float scale = RATE / (float)(*bn_p);

    // ---- pass 2: meta-MLP accumulation (streams L1/L2-hot from pass 1) ----
    // Dual accumulators (e-parity) to break the acc dependence chain.
    f2 accA = splat2(0.f), accB = splat2(0.f);
    for (int it = 0; it < ITERS; ++it) {
        const int base = it * 256 + lane * 4;
        const f4 wv4 = *(const f4*)(wrow + base);
        const f4 av4 = *(const f4*)(arow + base);
#pragma unroll
        for (int e = 0; e < 4; ++e) {
            const f2 wvE = splat2(wv4[e]);
            const f2 aE  = splat2(av4[e]);
            f2 t = splat2(0.f);
#pragma unroll
            for (int j = 0; j < 4; ++j) {
                f2 z = vfma2(wvE, q2[j], K2[j]);
                z = vfma2(aE, p2[j], z);
                const f2 u = __builtin_elementwise_max(z, splat2(0.f));
                t = vfma2(u, c22[j], t);
            }
            if (e & 1) accB = vfma2(aE, t, accB);
            else       accA = vfma2(aE, t, accA);
        }
    }
    const f2 acc = accA + accB;
    float r = acc.x + acc.y;
#pragma unroll
    for (int off = 1; off < 64; off <<= 1) r += __shfl_xor(r, off, 64);

    if (lane == 0) out[(size_t)b * O + o] = vj + scale * (r + c2b * ss);
}

extern "C" void kernel_launch(void* const* d_in, const int* in_sizes, int n_in,
                              void* d_out, int out_size, void* d_ws, size_t ws_size,
                              hipStream_t stream) {
    const float* x   = (const float*)d_in[0];   // (8, 1024)
    const float* w1  = (const float*)d_in[1];   // (2048, 1024)
    const float* b1  = (const float*)d_in[2];   // (2048,)
    const float* w2  = (const float*)d_in[3];   // (512, 2048)
    const float* b2  = (const float*)d_in[4];   // (512,)
    const float* c1w = (const float*)d_in[5];   // (8, 3)
    const float* c1b = (const float*)d_in[6];   // (8,)
    const float* c2w = (const float*)d_in[7];   // (8,)
    const float* c2b = (const float*)d_in[8];   // ()
    const int*   bn  = (const int*)d_in[9];     // scalar

    float* out = (float*)d_out;                 // (8, 512) fp32
    float* mid = (float*)d_ws;                  // (8, 2048) fp32 = 64 KB

    hebb_layer<1024><<<2048, 512, 0, stream>>>(x,   w1, b1, c1w, c1b, c2w, c2b, bn, mid, 2048);
    hebb_layer<2048><<<512,  512, 0, stream>>>(mid, w2, b2, c1w, c1b, c2w, c2b, bn, out, 512);
}